// Round 12
// baseline (91.468 us; speedup 1.0000x reference)
//
#include <hip/hip_runtime.h>

typedef __attribute__((ext_vector_type(2))) _Float16 h2;
typedef __attribute__((ext_vector_type(2))) __fp16 p2;   // cvt_pkrtz return type
typedef __attribute__((ext_vector_type(8))) _Float16 f16x8;
typedef __attribute__((ext_vector_type(4))) float fv4;
typedef __attribute__((ext_vector_type(4))) int iv4;
typedef unsigned int u32;

#define K_IN 4096
#define N_OUT 4096
#define NG 520    /* granules (8 f16) per extended row: 512 main + 8 ext */

// ws layout (bytes)
#define WN_OFF  0u                 /* u32 [256cb][512g][16rl]  = 8,388,608  */
#define SCA_OFF 8388608u           /* f16 [256cb][256gi][16rl] = 2,097,152  */
#define WL_OFF  10485760u          /* f16 [256cb][8g][16rl][8] =   524,288  */
#define XP_OFF  11010048u          /* f16 [64rb][520g][16rl][8]= 8,519,680  */

// Fragment-major: element (row,k) at [((row>>4)*G + (k>>3))*16 + (row&15)]
// -> one wave MFMA fragment = contiguous block (lane l = (k-gran l>>4, row l&15)).

// ---------------------------------------------------------------------------
// ONE prep launch, grid split:
//   bid < 1024        : xa dots for row b=bid + write xp ext granules 512..519
//   1024 <= bid <1280 : W nibble-pack + scales, col-block cb = bid-1024
//   1280 <= bid <1344 : xp main granules, row-block rb = bid-1280
// ---------------------------------------------------------------------------
__global__ __launch_bounds__(256) void prep_one(
        const float* __restrict__ x, const float* __restrict__ la,
        const int* __restrict__ qw, const float* __restrict__ sc,
        const float* __restrict__ lb, const float* __restrict__ alphap,
        char* __restrict__ ws)
{
    int bid = blockIdx.x;
    int t = threadIdx.x;
    __shared__ float red[4][16];

    if (bid < 1024) {
        // ---- xa dots (coalesced x read) + ext granules of xp ----
        int b = bid, rb = b >> 4, rl = b & 15;
        const fv4* xp4 = (const fv4*)(x + (size_t)b * K_IN);
        fv4 xv[4];
#pragma unroll
        for (int j = 0; j < 4; ++j) xv[j] = xp4[t + j * 256];
        float acc[16];
#pragma unroll
        for (int r = 0; r < 16; ++r) {
            const fv4* ap = (const fv4*)(la + (size_t)r * K_IN);
            float s = 0.f;
#pragma unroll
            for (int j = 0; j < 4; ++j) {
                fv4 av = ap[t + j * 256];
                s = fmaf(xv[j].x, av.x, s);
                s = fmaf(xv[j].y, av.y, s);
                s = fmaf(xv[j].z, av.z, s);
                s = fmaf(xv[j].w, av.w, s);
            }
            acc[r] = s;
        }
#pragma unroll
        for (int r = 0; r < 16; ++r) {
#pragma unroll
            for (int off = 1; off < 64; off <<= 1)
                acc[r] += __shfl_xor(acc[r], off);
        }
        int lane = t & 63, w = t >> 6;
        if (lane < 16) red[w][lane] = acc[lane];
        __syncthreads();
        if (t < 8) {
            int gl = t;                       // ext granule 512+gl
            union { p2 h[4]; iv4 v; } u;
            u.v = iv4{0, 0, 0, 0};
            if (gl < 2) {
#pragma unroll
                for (int e2 = 0; e2 < 4; ++e2) {
                    int k0 = gl * 8 + e2 * 2;
                    float v0 = red[0][k0] + red[1][k0] + red[2][k0] + red[3][k0];
                    float v1 = red[0][k0+1] + red[1][k0+1] + red[2][k0+1] + red[3][k0+1];
                    u.h[e2] = __builtin_amdgcn_cvt_pkrtz(v0, v1);
                }
            }
            _Float16* xpo = (_Float16*)(ws + XP_OFF);
            *(iv4*)(xpo + (((size_t)rb * NG + 512 + gl) * 16 + rl) * 8) = u.v;
        }
    } else if (bid < 1280) {
        // ---- W nibble pack + scales + lora f16 cols, col-block cb ----
        int cb = bid - 1024;
        u32* wn = (u32*)(ws + WN_OFF);
        _Float16* sca = (_Float16*)(ws + SCA_OFF);
#pragma unroll 1
        for (int it = 0; it < 32; ++it) {
            int idx = it * 256 + t;
            int g = idx >> 4, rl = idx & 15;
            int o = cb * 16 + rl;
            int gi = g >> 1, half = g & 1;
            const int* qp = qw + ((size_t)o * 256 + gi) * 8 + half * 4;
            iv4 q = *(const iv4*)qp;
            u32 d = (u32)(q.x & 0xFF) | ((u32)(q.y & 0xFF) << 8) |
                    ((u32)(q.z & 0xFF) << 16) | ((u32)(q.w & 0xFF) << 24);
            wn[((size_t)cb * 512 + g) * 16 + rl] = d;
            if (half == 0) {
                float s = sc[(size_t)o * 256 + gi];
                sca[((size_t)cb * 256 + gi) * 16 + rl] = (_Float16)(s * (2.0f / 15.0f));
            }
        }
        if (t < 128) {
            int gl = t >> 4, rl = t & 15;
            int o = cb * 16 + rl;
            union { p2 h[4]; iv4 v; } u;
            u.v = iv4{0, 0, 0, 0};
            if (gl < 2) {
                float al = alphap[0];
                const float* wp = lb + (size_t)o * 16 + gl * 8;
#pragma unroll
                for (int e = 0; e < 4; ++e)
                    u.h[e] = __builtin_amdgcn_cvt_pkrtz(al * wp[2 * e], al * wp[2 * e + 1]);
            }
            _Float16* wl = (_Float16*)(ws + WL_OFF);
            *(iv4*)(wl + (((size_t)cb * 8 + gl) * 16 + rl) * 8) = u.v;
        }
    } else {
        // ---- xp main granules, row-block rb ----
        int rb = bid - 1280;
        _Float16* xpo = (_Float16*)(ws + XP_OFF);
#pragma unroll 1
        for (int it = 0; it < 32; ++it) {
            int idx = it * 256 + t;
            int g = idx >> 4, rl = idx & 15;
            int b = rb * 16 + rl;
            const float* p = x + (size_t)b * K_IN + g * 8;
            fv4 v0 = *(const fv4*)(p);
            fv4 v1 = *(const fv4*)(p + 4);
            union { p2 h[4]; iv4 v; } u;
            u.h[0] = __builtin_amdgcn_cvt_pkrtz(v0.x, v0.y);
            u.h[1] = __builtin_amdgcn_cvt_pkrtz(v0.z, v0.w);
            u.h[2] = __builtin_amdgcn_cvt_pkrtz(v1.x, v1.y);
            u.h[3] = __builtin_amdgcn_cvt_pkrtz(v1.z, v1.w);
            *(iv4*)(xpo + (((size_t)rb * NG + g) * 16 + rl) * 8) = u.v;
        }
    }
}

// ---------------------------------------------------------------------------
// GEMM: out = X[1024][4160] @ W[4096][4160]^T, f32 accum.
// 256 blocks x 512 thr (8 waves: wm,wn,kg = 2x2x2; wave 64x64 over its k32
// half of each BK=64 step). No LDS/barriers in main loop; fragments loaded
// straight from L2: A = f16 (1KB/frag), B = packed nibbles (256B) + f16
// scale (32B bcast). In-loop dequant: v_perm byte-expand + pk_add/pk_fma.
// Step 65 (k 4096..4159) uses the f16 side-array Wl (lora + zero pad).
// ---------------------------------------------------------------------------
__global__ __launch_bounds__(512, 1) void qlora_gemm2(
        const char* __restrict__ ws, float* __restrict__ out)
{
    __shared__ __align__(16) char lds[65536];

    const _Float16* xp = (const _Float16*)(ws + XP_OFF);
    const u32* wn = (const u32*)(ws + WN_OFF);
    const unsigned short* sca = (const unsigned short*)(ws + SCA_OFF);
    const _Float16* wl = (const _Float16*)(ws + WL_OFF);

    int bid = blockIdx.x;
    int xcd = bid & 7, j = bid >> 3;    // j 0..31
    int by = j & 7, bx = xcd * 4 + (j >> 3);
    int bm0 = by << 7, bn0 = bx << 7;

    int t = threadIdx.x;
    int lane = t & 63;
    int wid = t >> 6;                   // 0..7
    int kg = wid & 1, wn_ = (wid >> 1) & 1, wm = wid >> 2;
    int rl = lane & 15, hq = lane >> 4;

    // per-lane fragment bases (granule g = ts*8 + kg*4 + hq)
    const char* abase[4];
    const u32* nbase[4];
    const unsigned short* sbase[4];
    const char* lbase[4];
#pragma unroll
    for (int m = 0; m < 4; ++m) {
        int rb = by * 8 + wm * 4 + m;
        abase[m] = (const char*)xp + (((size_t)rb * NG + kg * 4 + hq) * 16 + rl) * 16;
    }
#pragma unroll
    for (int n = 0; n < 4; ++n) {
        int cb = bx * 8 + wn_ * 4 + n;
        nbase[n] = wn + ((size_t)cb * 512 + kg * 4 + hq) * 16 + rl;
        sbase[n] = sca + ((size_t)cb * 256 + kg * 2 + (hq >> 1)) * 16 + rl;
        lbase[n] = (const char*)wl + (((size_t)cb * 8 + kg * 4 + hq) * 16 + rl) * 16;
    }

    struct FragM { iv4 a[4]; u32 bn[4]; u32 sc[4]; };
    struct FragL { iv4 a[4]; iv4 b[4]; };
    FragM fA, fB;
    FragL fL;

    auto LOADM = [&](FragM& f, int ts) {
        size_t aoff = (size_t)ts * 2048;
#pragma unroll
        for (int m = 0; m < 4; ++m) f.a[m] = *(const iv4*)(abase[m] + aoff);
#pragma unroll
        for (int n = 0; n < 4; ++n) {
            f.bn[n] = nbase[n][(size_t)ts * 128];
            f.sc[n] = sbase[n][(size_t)ts * 64];
        }
    };
    auto LOADL = [&](FragL& f) {
        size_t aoff = (size_t)64 * 2048;
#pragma unroll
        for (int m = 0; m < 4; ++m) f.a[m] = *(const iv4*)(abase[m] + aoff);
#pragma unroll
        for (int n = 0; n < 4; ++n) f.b[n] = *(const iv4*)(lbase[n]);
    };

    fv4 acc[4][4];
#pragma unroll
    for (int m = 0; m < 4; ++m)
#pragma unroll
        for (int n = 0; n < 4; ++n)
            acc[m][n] = fv4{0.f, 0.f, 0.f, 0.f};

    auto MFMAM = [&](const FragM& f) {
        union { iv4 v; f16x8 h; } ua[4];
#pragma unroll
        for (int m = 0; m < 4; ++m) ua[m].v = f.a[m];
        f16x8 b[4];
#pragma unroll
        for (int n = 0; n < 4; ++n) {
            u32 sv = f.sc[n];
            u32 s2 = sv | (sv << 16);
            h2 c0, c1;
            __builtin_memcpy(&c0, &s2, 4);
            c1 = c0 * h2{(_Float16)-7.5f, (_Float16)-7.5f};
            u32 d = f.bn[n];
            u32 dlo = d & 0x0F0F0F0Fu;
            u32 dhi = (d >> 4) & 0x0F0F0F0Fu;
            union { h2 hh[4]; f16x8 v; } ub;
#pragma unroll
            for (int i = 0; i < 4; ++i) {
                u32 sel = 0x0C000C00u | ((u32)(4 + i) << 16) | (u32)i;
                u32 w = __builtin_amdgcn_perm(dhi, dlo, sel) | 0x64006400u;
                h2 q;
                __builtin_memcpy(&q, &w, 4);
                q = q + h2{(_Float16)-1024.f, (_Float16)-1024.f};
                ub.hh[i] = q * c0 + c1;
            }
            b[n] = ub.v;
        }
        __builtin_amdgcn_s_setprio(1);
#pragma unroll
        for (int m = 0; m < 4; ++m)
#pragma unroll
            for (int n = 0; n < 4; ++n)
                acc[m][n] = __builtin_amdgcn_mfma_f32_16x16x32_f16(
                    ua[m].h, b[n], acc[m][n], 0, 0, 0);
        __builtin_amdgcn_s_setprio(0);
    };
    auto MFMAL = [&](const FragL& f) {
        union { iv4 v; f16x8 h; } ua[4], ub[4];
#pragma unroll
        for (int m = 0; m < 4; ++m) ua[m].v = f.a[m];
#pragma unroll
        for (int n = 0; n < 4; ++n) ub[n].v = f.b[n];
#pragma unroll
        for (int m = 0; m < 4; ++m)
#pragma unroll
            for (int n = 0; n < 4; ++n)
                acc[m][n] = __builtin_amdgcn_mfma_f32_16x16x32_f16(
                    ua[m].h, ub[n].h, acc[m][n], 0, 0, 0);
    };

    // ---- main loop: 64 nibble steps + 1 f16 ext step; reg double-buffer ----
    LOADM(fA, 0);
#pragma unroll 1
    for (int ts = 0; ts < 64; ts += 2) {
        LOADM(fB, ts + 1);
        MFMAM(fA);
        if (ts + 2 < 64) LOADM(fA, ts + 2);
        else             LOADL(fL);
        MFMAM(fB);
    }
    MFMAL(fL);

    // ---- kg-split reduction + store ----
    __syncthreads();
    if (kg == 1) {
        char* dmp = lds + (wm * 2 + wn_) * 16384;
#pragma unroll
        for (int m = 0; m < 4; ++m)
#pragma unroll
            for (int n = 0; n < 4; ++n)
                *(fv4*)(dmp + (m * 4 + n) * 1024 + lane * 16) = acc[m][n];
    }
    __syncthreads();
    if (kg == 0) {
        const char* dmp = lds + (wm * 2 + wn_) * 16384;
#pragma unroll
        for (int m = 0; m < 4; ++m) {
            int row0 = bm0 + wm * 64 + m * 16 + hq * 4;
#pragma unroll
            for (int n = 0; n < 4; ++n) {
                fv4 p = *(const fv4*)(dmp + (m * 4 + n) * 1024 + lane * 16);
                fv4 v = acc[m][n];
                v.x += p.x; v.y += p.y; v.z += p.z; v.w += p.w;
                int col = bn0 + wn_ * 64 + n * 16 + rl;
#pragma unroll
                for (int r = 0; r < 4; ++r)
                    out[(size_t)(row0 + r) * N_OUT + col] = v[r];
            }
        }
    }
}

extern "C" void kernel_launch(void* const* d_in, const int* in_sizes, int n_in,
                              void* d_out, int out_size, void* d_ws, size_t ws_size,
                              hipStream_t stream) {
    const float* x  = (const float*)d_in[0];
    const int*   qw = (const int*)d_in[1];
    const float* sc = (const float*)d_in[2];
    const float* la = (const float*)d_in[3];
    const float* lb = (const float*)d_in[4];
    const float* al = (const float*)d_in[5];
    float* out = (float*)d_out;
    char* ws = (char*)d_ws;
    (void)ws_size; (void)n_in; (void)in_sizes; (void)out_size;

    prep_one<<<1344, 256, 0, stream>>>(x, la, qw, sc, lb, al, ws);
    qlora_gemm2<<<256, 512, 0, stream>>>(ws, out);
}

// Round 13
// 77.821 us; speedup vs baseline: 1.1754x; 1.1754x over previous
//
#include <hip/hip_runtime.h>

typedef __attribute__((ext_vector_type(2))) _Float16 h2;
typedef __attribute__((ext_vector_type(2))) __fp16 p2;   // cvt_pkrtz return type
typedef __attribute__((ext_vector_type(8))) _Float16 f16x8;
typedef __attribute__((ext_vector_type(4))) float fv4;
typedef __attribute__((ext_vector_type(4))) int iv4;
typedef __attribute__((ext_vector_type(2))) int iv2;
typedef unsigned int u32;

#define K_IN 4096
#define N_OUT 4096
#define NG 520    /* granules (8 f16) per extended row: 512 main + 8 ext */

// Fragment-major: f16 element (row,k) lives at
//   [(((row>>4)*NG + (k>>3))*16 + (row&15))*8 + (k&7)]
// One wave MFMA fragment (granule g, 16 rows) = contiguous 256B; a 4-granule
// lane-set (hq in 0..3) = contiguous 1KB global_load_dwordx4 per lane.

// ---------------------------------------------------------------------------
// ONE prep launch, grid split (1536 blocks):
//   bid <  1024        : xa dots row b=bid -> xp ext granules 512..519
//   1024 <= bid < 1280 : W dequant col-block cb (LDS transpose, coalesced)
//   1280 <= bid < 1536 : xp main granules (rb, k-quarter)  (LDS transpose)
// ---------------------------------------------------------------------------
__global__ __launch_bounds__(256) void prep_one(
        const float* __restrict__ x, const float* __restrict__ la,
        const int* __restrict__ qw, const float* __restrict__ sc,
        const float* __restrict__ lb, const float* __restrict__ alphap,
        _Float16* __restrict__ Wp, _Float16* __restrict__ xp)
{
    __shared__ __align__(16) char lsm[16640];
    int bid = blockIdx.x;
    int t = threadIdx.x;

    if (bid < 1024) {
        // ---- xa dots (coalesced x read) + ext granules of xp ----
        float (*red)[16] = (float (*)[16])(lsm + 16384);
        int b = bid, rb = b >> 4, rl = b & 15;
        const fv4* xp4 = (const fv4*)(x + (size_t)b * K_IN);
        fv4 xv[4];
#pragma unroll
        for (int j = 0; j < 4; ++j) xv[j] = xp4[t + j * 256];
        float acc[16];
#pragma unroll
        for (int r = 0; r < 16; ++r) {
            const fv4* ap = (const fv4*)(la + (size_t)r * K_IN);
            float s = 0.f;
#pragma unroll
            for (int j = 0; j < 4; ++j) {
                fv4 av = ap[t + j * 256];
                s = fmaf(xv[j].x, av.x, s);
                s = fmaf(xv[j].y, av.y, s);
                s = fmaf(xv[j].z, av.z, s);
                s = fmaf(xv[j].w, av.w, s);
            }
            acc[r] = s;
        }
#pragma unroll
        for (int r = 0; r < 16; ++r) {
#pragma unroll
            for (int off = 1; off < 64; off <<= 1)
                acc[r] += __shfl_xor(acc[r], off);
        }
        int lane = t & 63, w = t >> 6;
        if (lane < 16) red[w][lane] = acc[lane];
        __syncthreads();
        if (t < 8) {
            int gl = t;                       // ext granule 512+gl
            union { p2 h[4]; iv4 v; } u;
            u.v = iv4{0, 0, 0, 0};
            if (gl < 2) {
#pragma unroll
                for (int e2 = 0; e2 < 4; ++e2) {
                    int k0 = gl * 8 + e2 * 2;
                    float v0 = red[0][k0] + red[1][k0] + red[2][k0] + red[3][k0];
                    float v1 = red[0][k0+1] + red[1][k0+1] + red[2][k0+1] + red[3][k0+1];
                    u.h[e2] = __builtin_amdgcn_cvt_pkrtz(v0, v1);
                }
            }
            *(iv4*)(xp + (((size_t)rb * NG + 512 + gl) * 16 + rl) * 8) = u.v;
        }
    } else if (bid < 1280) {
        // ---- W dequant, col-block cb: LDS transpose, both sides coalesced ----
        int cb = bid - 1024;
        int o_l = t >> 4, gi_l = t & 15;
#pragma unroll 1
        for (int chunk = 0; chunk < 8; ++chunk) {
#pragma unroll
            for (int i = 0; i < 2; ++i) {
                int gi = chunk * 32 + i * 16 + gi_l;
                int o = cb * 16 + o_l;
                const int* qp = qw + ((size_t)o * 256 + gi) * 8;
                iv4 q0 = *(const iv4*)qp;
                iv4 q1 = *(const iv4*)(qp + 4);
                float s = sc[(size_t)o * 256 + gi];
                _Float16 c0h = (_Float16)(s * (2.0f / 15.0f));
                _Float16 c1h = (_Float16)(-s);
                h2 c0 = {c0h, c0h}, c1 = {c1h, c1h};
                h2 m1024 = {(_Float16)-1024.f, (_Float16)-1024.f};
                union { h2 h[4]; iv4 v; } w0, w1;
                int vals[8] = {q0.x, q0.y, q0.z, q0.w, q1.x, q1.y, q1.z, q1.w};
#pragma unroll
                for (int e = 0; e < 8; ++e) {
                    unsigned wv = (unsigned)vals[e];
                    unsigned qb = (wv & 15u) | ((wv & 0xF0u) << 12) | 0x64006400u;
                    h2 qh;
                    __builtin_memcpy(&qh, &qb, 4);
                    h2 r = (qh + m1024) * c0 + c1;
                    if (e < 4) w0.h[e] = r; else w1.h[e - 4] = r;
                }
                // chunk-local granules gl0 = i*32 + 2*gi_l, gl0+1
                int gl0 = i * 32 + 2 * gi_l;
                int s0 = o_l ^ gi_l;          // swizzle: (gl>>1)&15 == gi_l
                *(iv4*)(lsm + (gl0 * 16 + s0) * 16) = w0.v;
                *(iv4*)(lsm + ((gl0 + 1) * 16 + s0) * 16) = w1.v;
            }
            __syncthreads();
#pragma unroll
            for (int i = 0; i < 4; ++i) {
                int s_ = t + i * 256;          // 0..1023: gl = s_>>4, o = s_&15
                int gl = s_ >> 4, oo = s_ & 15;
                iv4 v = *(const iv4*)(lsm + (gl * 16 + (oo ^ ((gl >> 1) & 15))) * 16);
                *(iv4*)(Wp + (((size_t)cb * NG + chunk * 64) * 16 + s_) * 8) = v;
            }
            __syncthreads();
        }
        // lora ext granules 512..519
        if (t < 128) {
            int gl = t >> 4, rl = t & 15;
            int o = cb * 16 + rl;
            union { p2 h[4]; iv4 v; } u;
            u.v = iv4{0, 0, 0, 0};
            if (gl < 2) {
                float al = alphap[0];
                const float* wp = lb + (size_t)o * 16 + gl * 8;
#pragma unroll
                for (int e = 0; e < 4; ++e)
                    u.h[e] = __builtin_amdgcn_cvt_pkrtz(al * wp[2 * e], al * wp[2 * e + 1]);
            }
            *(iv4*)(Wp + (((size_t)cb * NG + 512 + gl) * 16 + rl) * 8) = u.v;
        }
    } else {
        // ---- xp main granules, (rb, k-quarter): LDS transpose ----
        int q2 = bid - 1280;
        int rb = q2 >> 2, kq = q2 & 3;
        int row = t >> 4, q = t & 15;
#pragma unroll 1
        for (int chunk = 0; chunk < 2; ++chunk) {
            int base_k = kq * 1024 + chunk * 512;
#pragma unroll
            for (int i = 0; i < 8; ++i) {
                int quad = q + i * 16;         // 0..127
                const float* p = x + (size_t)(rb * 16 + row) * K_IN + base_k + quad * 4;
                fv4 v = *(const fv4*)p;
                union { p2 h[2]; iv2 vv; } u;
                u.h[0] = __builtin_amdgcn_cvt_pkrtz(v.x, v.y);
                u.h[1] = __builtin_amdgcn_cvt_pkrtz(v.z, v.w);
                int gl = quad >> 1, sub = quad & 1;
                *(iv2*)(lsm + (gl * 16 + (row ^ (gl & 15))) * 16 + sub * 8) = u.vv;
            }
            __syncthreads();
#pragma unroll
            for (int i = 0; i < 4; ++i) {
                int s_ = t + i * 256;          // gl = s_>>4, row = s_&15
                int gl = s_ >> 4, rr = s_ & 15;
                iv4 v = *(const iv4*)(lsm + (gl * 16 + (rr ^ (gl & 15))) * 16);
                *(iv4*)(xp + (((size_t)rb * NG + kq * 128 + chunk * 64) * 16 + s_) * 8) = v;
            }
            __syncthreads();
        }
    }
}

// ---------------------------------------------------------------------------
// GEMM (R11, proven ~30us): out = X[1024][4160] @ W[4096][4160]^T, f32 accum.
// 256 blocks x 512 thr (8 waves: wm,wn,kg=2x2x2; wave 64x64 over its k32
// half of each BK=64 step; 65 steps). No LDS/barriers in main loop; each
// fragment is one contiguous 1KB global_load_dwordx4 from L2; dist-1 register
// double-buffer. LDS (64KB) only for the kg-split epilogue reduction.
// ---------------------------------------------------------------------------
__global__ __launch_bounds__(512, 1) void qlora_gemm2(
        const _Float16* __restrict__ xp, const _Float16* __restrict__ Wp,
        float* __restrict__ out)
{
    __shared__ __align__(16) char lds[65536];

    int bid = blockIdx.x;
    int xcd = bid & 7, j = bid >> 3;    // j 0..31
    int by = j & 7, bx = xcd * 4 + (j >> 3);
    int bm0 = by << 7, bn0 = bx << 7;

    int t = threadIdx.x;
    int lane = t & 63;
    int wid = t >> 6;                   // 0..7
    int kg = wid & 1, wn = (wid >> 1) & 1, wm = wid >> 2;
    int rl = lane & 15, hq = lane >> 4;

    const char* abase[4];
    const char* bbase[4];
#pragma unroll
    for (int m = 0; m < 4; ++m) {
        int rb = by * 8 + wm * 4 + m;
        abase[m] = (const char*)xp + (((size_t)rb * NG + kg * 4 + hq) * 16 + rl) * 16;
    }
#pragma unroll
    for (int n = 0; n < 4; ++n) {
        int cb = bx * 8 + wn * 4 + n;
        bbase[n] = (const char*)Wp + (((size_t)cb * NG + kg * 4 + hq) * 16 + rl) * 16;
    }

    struct Frag { iv4 a[4]; iv4 b[4]; };
    Frag fA, fB;

    auto LOADF = [&](Frag& f, int ts) {
        size_t off = (size_t)ts * 2048;   // 8 granules * 256B
#pragma unroll
        for (int m = 0; m < 4; ++m) f.a[m] = *(const iv4*)(abase[m] + off);
#pragma unroll
        for (int n = 0; n < 4; ++n) f.b[n] = *(const iv4*)(bbase[n] + off);
    };

    fv4 acc[4][4];
#pragma unroll
    for (int m = 0; m < 4; ++m)
#pragma unroll
        for (int n = 0; n < 4; ++n)
            acc[m][n] = fv4{0.f, 0.f, 0.f, 0.f};

    auto MFMAF = [&](const Frag& f) {
        union { iv4 v; f16x8 h; } ua[4], ub[4];
#pragma unroll
        for (int m = 0; m < 4; ++m) ua[m].v = f.a[m];
#pragma unroll
        for (int n = 0; n < 4; ++n) ub[n].v = f.b[n];
        __builtin_amdgcn_s_setprio(1);
#pragma unroll
        for (int m = 0; m < 4; ++m)
#pragma unroll
            for (int n = 0; n < 4; ++n)
                acc[m][n] = __builtin_amdgcn_mfma_f32_16x16x32_f16(
                    ua[m].h, ub[n].h, acc[m][n], 0, 0, 0);
        __builtin_amdgcn_s_setprio(0);
    };

    // ---- main loop: 65 steps, register double-buffer, no barriers ----
    LOADF(fA, 0);
#pragma unroll 1
    for (int ts = 0; ts < 64; ts += 2) {
        LOADF(fB, ts + 1);
        MFMAF(fA);
        LOADF(fA, ts + 2);
        MFMAF(fB);
    }
    MFMAF(fA);                           // ts = 64 (ext/lora step)

    // ---- kg-split reduction + store ----
    __syncthreads();
    if (kg == 1) {
        char* dmp = lds + (wm * 2 + wn) * 16384;
#pragma unroll
        for (int m = 0; m < 4; ++m)
#pragma unroll
            for (int n = 0; n < 4; ++n)
                *(fv4*)(dmp + (m * 4 + n) * 1024 + lane * 16) = acc[m][n];
    }
    __syncthreads();
    if (kg == 0) {
        const char* dmp = lds + (wm * 2 + wn) * 16384;
#pragma unroll
        for (int m = 0; m < 4; ++m) {
            int row0 = bm0 + wm * 64 + m * 16 + hq * 4;
#pragma unroll
            for (int n = 0; n < 4; ++n) {
                fv4 p = *(const fv4*)(dmp + (m * 4 + n) * 1024 + lane * 16);
                fv4 v = acc[m][n];
                v.x += p.x; v.y += p.y; v.z += p.z; v.w += p.w;
                int col = bn0 + wn * 64 + n * 16 + rl;
#pragma unroll
                for (int r = 0; r < 4; ++r)
                    out[(size_t)(row0 + r) * N_OUT + col] = v[r];
            }
        }
    }
}

extern "C" void kernel_launch(void* const* d_in, const int* in_sizes, int n_in,
                              void* d_out, int out_size, void* d_ws, size_t ws_size,
                              hipStream_t stream) {
    const float* x  = (const float*)d_in[0];
    const int*   qw = (const int*)d_in[1];
    const float* sc = (const float*)d_in[2];
    const float* la = (const float*)d_in[3];
    const float* lb = (const float*)d_in[4];
    const float* al = (const float*)d_in[5];
    float* out = (float*)d_out;

    const size_t WP_BYTES = (size_t)256 * NG * 16 * 16;   // 34,078,720
    _Float16* Wp = (_Float16*)d_ws;
    _Float16* xp = (_Float16*)((char*)d_ws + WP_BYTES);
    (void)ws_size; (void)n_in; (void)in_sizes; (void)out_size;

    prep_one<<<1536, 256, 0, stream>>>(x, la, qw, sc, lb, al, Wp, xp);
    qlora_gemm2<<<256, 512, 0, stream>>>(xp, Wp, out);
}

// Round 14
// 75.387 us; speedup vs baseline: 1.2133x; 1.0323x over previous
//
#include <hip/hip_runtime.h>

typedef __attribute__((ext_vector_type(2))) _Float16 h2;
typedef __attribute__((ext_vector_type(2))) __fp16 p2;   // cvt_pkrtz return type
typedef __attribute__((ext_vector_type(8))) _Float16 f16x8;
typedef __attribute__((ext_vector_type(4))) float fv4;
typedef __attribute__((ext_vector_type(4))) int iv4;
typedef __attribute__((ext_vector_type(2))) int iv2;
typedef unsigned int u32;

#define K_IN 4096
#define N_OUT 4096
#define NG 520    /* granules (8 f16) per extended row: 512 main + 8 ext */

// Fragment-major: f16 element (row,k) lives at
//   [(((row>>4)*NG + (k>>3))*16 + (row&15))*8 + (k&7)]
// One wave MFMA fragment (16 rows x 4 granules) = contiguous 1KB per lane-set.

// ---------------------------------------------------------------------------
// ONE prep launch, grid split (2304 blocks):
//   bid <  1024        : xa dots row b=bid -> xp ext granules 512..519
//   1024 <= bid < 2048 : W dequant (cb = idx>>2, chunk-pair = idx&3)
//   2048 <= bid < 2304 : xp main granules (rb, k-quarter)  (LDS transpose)
// ---------------------------------------------------------------------------
__global__ __launch_bounds__(256) void prep_one(
        const float* __restrict__ x, const float* __restrict__ la,
        const int* __restrict__ qw, const float* __restrict__ sc,
        const float* __restrict__ lb, const float* __restrict__ alphap,
        _Float16* __restrict__ Wp, _Float16* __restrict__ xp)
{
    __shared__ __align__(16) char lsm[16640];
    int bid = blockIdx.x;
    int t = threadIdx.x;

    if (bid < 1024) {
        // ---- xa dots (coalesced x read) + ext granules of xp ----
        float (*red)[16] = (float (*)[16])(lsm + 16384);
        int b = bid, rb = b >> 4, rl = b & 15;
        const fv4* xp4 = (const fv4*)(x + (size_t)b * K_IN);
        fv4 xv[4];
#pragma unroll
        for (int j = 0; j < 4; ++j) xv[j] = xp4[t + j * 256];
        float acc[16];
#pragma unroll
        for (int r = 0; r < 16; ++r) {
            const fv4* ap = (const fv4*)(la + (size_t)r * K_IN);
            float s = 0.f;
#pragma unroll
            for (int j = 0; j < 4; ++j) {
                fv4 av = ap[t + j * 256];
                s = fmaf(xv[j].x, av.x, s);
                s = fmaf(xv[j].y, av.y, s);
                s = fmaf(xv[j].z, av.z, s);
                s = fmaf(xv[j].w, av.w, s);
            }
            acc[r] = s;
        }
#pragma unroll
        for (int r = 0; r < 16; ++r) {
#pragma unroll
            for (int off = 1; off < 64; off <<= 1)
                acc[r] += __shfl_xor(acc[r], off);
        }
        int lane = t & 63, w = t >> 6;
        if (lane < 16) red[w][lane] = acc[lane];
        __syncthreads();
        if (t < 8) {
            int gl = t;                       // ext granule 512+gl
            union { p2 h[4]; iv4 v; } u;
            u.v = iv4{0, 0, 0, 0};
            if (gl < 2) {
#pragma unroll
                for (int e2 = 0; e2 < 4; ++e2) {
                    int k0 = gl * 8 + e2 * 2;
                    float v0 = red[0][k0] + red[1][k0] + red[2][k0] + red[3][k0];
                    float v1 = red[0][k0+1] + red[1][k0+1] + red[2][k0+1] + red[3][k0+1];
                    u.h[e2] = __builtin_amdgcn_cvt_pkrtz(v0, v1);
                }
            }
            *(iv4*)(xp + (((size_t)rb * NG + 512 + gl) * 16 + rl) * 8) = u.v;
        }
    } else if (bid < 2048) {
        // ---- W dequant, (cb, chunk-pair): LDS transpose, coalesced both ways ----
        int idx = bid - 1024;
        int cb = idx >> 2, part = idx & 3;
        int c0 = part * 2;
        int o_l = t >> 4, gi_l = t & 15;
#pragma unroll 1
        for (int chunk = c0; chunk < c0 + 2; ++chunk) {
#pragma unroll
            for (int i = 0; i < 2; ++i) {
                int gi = chunk * 32 + i * 16 + gi_l;
                int o = cb * 16 + o_l;
                const int* qp = qw + ((size_t)o * 256 + gi) * 8;
                iv4 q0 = *(const iv4*)qp;
                iv4 q1 = *(const iv4*)(qp + 4);
                float s = sc[(size_t)o * 256 + gi];
                _Float16 c0h = (_Float16)(s * (2.0f / 15.0f));
                _Float16 c1h = (_Float16)(-s);
                h2 c0v = {c0h, c0h}, c1v = {c1h, c1h};
                h2 m1024 = {(_Float16)-1024.f, (_Float16)-1024.f};
                union { h2 h[4]; iv4 v; } w0, w1;
                int vals[8] = {q0.x, q0.y, q0.z, q0.w, q1.x, q1.y, q1.z, q1.w};
#pragma unroll
                for (int e = 0; e < 8; ++e) {
                    unsigned wv = (unsigned)vals[e];
                    unsigned qb = (wv & 15u) | ((wv & 0xF0u) << 12) | 0x64006400u;
                    h2 qh;
                    __builtin_memcpy(&qh, &qb, 4);
                    h2 r = (qh + m1024) * c0v + c1v;
                    if (e < 4) w0.h[e] = r; else w1.h[e - 4] = r;
                }
                int gl0 = i * 32 + 2 * gi_l;
                int s0 = o_l ^ gi_l;
                *(iv4*)(lsm + (gl0 * 16 + s0) * 16) = w0.v;
                *(iv4*)(lsm + ((gl0 + 1) * 16 + s0) * 16) = w1.v;
            }
            __syncthreads();
#pragma unroll
            for (int i = 0; i < 4; ++i) {
                int s_ = t + i * 256;          // 0..1023: gl = s_>>4, o = s_&15
                int gl = s_ >> 4, oo = s_ & 15;
                iv4 v = *(const iv4*)(lsm + (gl * 16 + (oo ^ ((gl >> 1) & 15))) * 16);
                *(iv4*)(Wp + (((size_t)cb * NG + chunk * 64) * 16 + s_) * 8) = v;
            }
            __syncthreads();
        }
        // lora ext granules 512..519 (once per cb)
        if (part == 0 && t < 128) {
            int gl = t >> 4, rl = t & 15;
            int o = cb * 16 + rl;
            union { p2 h[4]; iv4 v; } u;
            u.v = iv4{0, 0, 0, 0};
            if (gl < 2) {
                float al = alphap[0];
                const float* wp = lb + (size_t)o * 16 + gl * 8;
#pragma unroll
                for (int e = 0; e < 4; ++e)
                    u.h[e] = __builtin_amdgcn_cvt_pkrtz(al * wp[2 * e], al * wp[2 * e + 1]);
            }
            *(iv4*)(Wp + (((size_t)cb * NG + 512 + gl) * 16 + rl) * 8) = u.v;
        }
    } else {
        // ---- xp main granules, (rb, k-quarter): LDS transpose ----
        int q2 = bid - 2048;
        int rb = q2 >> 2, kq = q2 & 3;
        int row = t >> 4, q = t & 15;
#pragma unroll 1
        for (int chunk = 0; chunk < 2; ++chunk) {
            int base_k = kq * 1024 + chunk * 512;
#pragma unroll
            for (int i = 0; i < 8; ++i) {
                int quad = q + i * 16;         // 0..127
                const float* p = x + (size_t)(rb * 16 + row) * K_IN + base_k + quad * 4;
                fv4 v = *(const fv4*)p;
                union { p2 h[2]; iv2 vv; } u;
                u.h[0] = __builtin_amdgcn_cvt_pkrtz(v.x, v.y);
                u.h[1] = __builtin_amdgcn_cvt_pkrtz(v.z, v.w);
                int gl = quad >> 1, sub = quad & 1;
                *(iv2*)(lsm + (gl * 16 + (row ^ (gl & 15))) * 16 + sub * 8) = u.vv;
            }
            __syncthreads();
#pragma unroll
            for (int i = 0; i < 4; ++i) {
                int s_ = t + i * 256;          // gl = s_>>4, row = s_&15
                int gl = s_ >> 4, rr = s_ & 15;
                iv4 v = *(const iv4*)(lsm + (gl * 16 + (rr ^ (gl & 15))) * 16);
                *(iv4*)(xp + (((size_t)rb * NG + kq * 128 + chunk * 64) * 16 + s_) * 8) = v;
            }
            __syncthreads();
        }
    }
}

// ---------------------------------------------------------------------------
// GEMM v4: out = X[1024][4160] @ W[4096][4160]^T, f32 accum.
// 256 blocks x 256 thr (4 waves, wm x wn = 2x2, wave tile 64x64, FULL K --
// no kg-split, no LDS, no barriers, direct stores). 65 k64 steps; per step a
// wave issues 16 x 1KB contiguous global_load_dwordx4 (next step) then 32
// MFMA (current step), pinned with sched_group_barrier so regalloc cannot
// collapse the register double-buffer (R13 lesson: VGPR=80 => no prefetch).
// ---------------------------------------------------------------------------
__global__ __launch_bounds__(256, 1) void qlora_gemm2(
        const _Float16* __restrict__ xp, const _Float16* __restrict__ Wp,
        float* __restrict__ out)
{
    int bid = blockIdx.x;
    int xcd = bid & 7, j = bid >> 3;    // j 0..31
    int by = j & 7, bx = xcd * 4 + (j >> 3);
    int bm0 = by << 7, bn0 = bx << 7;

    int t = threadIdx.x;
    int lane = t & 63;
    int wid = t >> 6;                   // 0..3
    int wm = wid >> 1, wn = wid & 1;
    int rl = lane & 15, hq = lane >> 4;

    const char* abase[4];
    const char* bbase[4];
#pragma unroll
    for (int m = 0; m < 4; ++m) {
        int rb = by * 8 + wm * 4 + m;
        abase[m] = (const char*)xp + (((size_t)rb * NG + hq) * 16 + rl) * 16;
    }
#pragma unroll
    for (int n = 0; n < 4; ++n) {
        int cb = bx * 8 + wn * 4 + n;
        bbase[n] = (const char*)Wp + (((size_t)cb * NG + hq) * 16 + rl) * 16;
    }

    struct Frag { iv4 a[8]; iv4 b[8]; };   // [slice*4 + m]
    Frag fA, fB;

    auto LOADF = [&](Frag& f, int ts) {
        size_t off = (size_t)ts * 2048;      // 8 granules * 256B
#pragma unroll
        for (int s2 = 0; s2 < 2; ++s2) {
#pragma unroll
            for (int m = 0; m < 4; ++m)
                f.a[s2 * 4 + m] = *(const iv4*)(abase[m] + off + s2 * 1024);
#pragma unroll
            for (int n = 0; n < 4; ++n)
                f.b[s2 * 4 + n] = *(const iv4*)(bbase[n] + off + s2 * 1024);
        }
    };

    fv4 acc[4][4];
#pragma unroll
    for (int m = 0; m < 4; ++m)
#pragma unroll
        for (int n = 0; n < 4; ++n)
            acc[m][n] = fv4{0.f, 0.f, 0.f, 0.f};

    auto MFMAF = [&](const Frag& f) {
        __builtin_amdgcn_s_setprio(1);
#pragma unroll
        for (int s2 = 0; s2 < 2; ++s2) {
            union { iv4 v; f16x8 h; } ua[4], ub[4];
#pragma unroll
            for (int m = 0; m < 4; ++m) ua[m].v = f.a[s2 * 4 + m];
#pragma unroll
            for (int n = 0; n < 4; ++n) ub[n].v = f.b[s2 * 4 + n];
#pragma unroll
            for (int m = 0; m < 4; ++m)
#pragma unroll
                for (int n = 0; n < 4; ++n)
                    acc[m][n] = __builtin_amdgcn_mfma_f32_16x16x32_f16(
                        ua[m].h, ub[n].h, acc[m][n], 0, 0, 0);
        }
        __builtin_amdgcn_s_setprio(0);
    };

    // ---- main loop: 65 k64 steps, dist-1 register double-buffer ----
    LOADF(fA, 0);
#pragma unroll 1
    for (int ts = 0; ts < 64; ts += 2) {
        LOADF(fB, ts + 1);
        __builtin_amdgcn_sched_group_barrier(0x20, 16, 0);  // 16 VMEM reads
        MFMAF(fA);
        __builtin_amdgcn_sched_group_barrier(0x8, 32, 0);   // 32 MFMA
        LOADF(fA, ts + 2);
        __builtin_amdgcn_sched_group_barrier(0x20, 16, 0);
        MFMAF(fB);
        __builtin_amdgcn_sched_group_barrier(0x8, 32, 0);
    }
    MFMAF(fA);                           // ts = 64 (lora/ext step)

    // ---- direct store (C/D: col=lane&15, row=(lane>>4)*4+r) ----
#pragma unroll
    for (int m = 0; m < 4; ++m) {
        int row0 = bm0 + wm * 64 + m * 16 + hq * 4;
#pragma unroll
        for (int n = 0; n < 4; ++n) {
            int col = bn0 + wn * 64 + n * 16 + rl;
#pragma unroll
            for (int r = 0; r < 4; ++r)
                out[(size_t)(row0 + r) * N_OUT + col] = acc[m][n][r];
        }
    }
}

extern "C" void kernel_launch(void* const* d_in, const int* in_sizes, int n_in,
                              void* d_out, int out_size, void* d_ws, size_t ws_size,
                              hipStream_t stream) {
    const float* x  = (const float*)d_in[0];
    const int*   qw = (const int*)d_in[1];
    const float* sc = (const float*)d_in[2];
    const float* la = (const float*)d_in[3];
    const float* lb = (const float*)d_in[4];
    const float* al = (const float*)d_in[5];
    float* out = (float*)d_out;

    const size_t WP_BYTES = (size_t)256 * NG * 16 * 16;   // 34,078,720
    _Float16* Wp = (_Float16*)d_ws;
    _Float16* xp = (_Float16*)((char*)d_ws + WP_BYTES);
    (void)ws_size; (void)n_in; (void)in_sizes; (void)out_size;

    prep_one<<<2304, 256, 0, stream>>>(x, la, qw, sc, lb, al, Wp, xp);
    qlora_gemm2<<<256, 256, 0, stream>>>(xp, Wp, out);
}